// Round 4
// baseline (395.918 us; speedup 1.0000x reference)
//
#include <hip/hip_runtime.h>

typedef __attribute__((ext_vector_type(8))) __bf16 bf16x8;
typedef __attribute__((ext_vector_type(4))) float f32x4;

#define B_    128
#define DIM_  768
#define HALF_ 384
#define HW_   196
#define NPOS_ (B_*HW_)      /* 25088 */
#define IMG_  (DIM_*HW_)    /* 150528 */

typedef const __attribute__((address_space(1))) void* gas_t;
typedef __attribute__((address_space(3))) void* las_t;

__device__ __forceinline__ unsigned short f2bf(float f) {
  unsigned int u = __builtin_bit_cast(unsigned int, f);
  u = (u + 0x7FFFu + ((u >> 16) & 1u)) >> 16;
  return (unsigned short)u;
}

// ---------------------------------------------------------------------------
// Zero the BN stats accumulator (d_ws is poisoned 0xAA before every launch).
// ---------------------------------------------------------------------------
__global__ void k_zero(float* __restrict__ stats) {
  int i = blockIdx.x * 256 + threadIdx.x;
  if (i < 2 * DIM_) stats[i] = 0.f;
}

// ---------------------------------------------------------------------------
// w_spatial[c][y*14+x] from complex_weight (validated round 1)
// ---------------------------------------------------------------------------
__global__ void k_wspatial(const float* __restrict__ cw, float* __restrict__ wsp) {
  __shared__ float ct[14], st[14];
  const int c = blockIdx.x;
  const int tid = threadIdx.x;     // 0..195
  if (tid < 14) {
    float s, co;
    sincosf(0.44879895051282760549f * (float)tid, &s, &co);
    ct[tid] = co; st[tid] = s;
  }
  __syncthreads();
  const int y = tid / 14, xx = tid % 14;
  float acc = 0.f;
  for (int u = 0; u < 14; ++u) {
    #pragma unroll
    for (int v = 0; v < 8; ++v) {
      int idx = (u * y + v * xx) % 14;
      float wr = cw[(((size_t)c * 14 + u) * 8 + v) * 2 + 0];
      float wi = cw[(((size_t)c * 14 + u) * 8 + v) * 2 + 1];
      float fac = (v == 0 || v == 7) ? 1.f : 2.f;
      acc += fac * (wr * ct[idx] - wi * st[idx]);
    }
  }
  wsp[(size_t)c * 196 + tid] = acc * (1.f / 196.f);
}

// ---------------------------------------------------------------------------
// proj_weight fp32 -> bf16 [o][c]
// ---------------------------------------------------------------------------
__global__ void k_cvtW(const float* __restrict__ pw, unsigned short* __restrict__ Wb) {
  int i = blockIdx.x * 256 + threadIdx.x;
  float4 v = reinterpret_cast<const float4*>(pw)[i];
  unsigned int lo = (unsigned int)f2bf(v.x) | ((unsigned int)f2bf(v.y) << 16);
  unsigned int hi = (unsigned int)f2bf(v.z) | ((unsigned int)f2bf(v.w) << 16);
  reinterpret_cast<uint2*>(Wb)[i] = make_uint2(lo, hi);
}

// ---------------------------------------------------------------------------
// Depthwise 3x3 SAME (channels 0..383) -> featT[n][c] bf16
// ---------------------------------------------------------------------------
__global__ __launch_bounds__(256) void k_dwconv(
    const float* __restrict__ x, const float* __restrict__ dww,
    unsigned short* __restrict__ featT) {
  __shared__ __align__(16) float xin[16][196];
  __shared__ float wgt[16][9];
  __shared__ __align__(16) unsigned short outT[196][16];
  const int cgrp = blockIdx.x;
  const int b = blockIdx.y;
  const int c0 = cgrp * 16;
  const int tid = threadIdx.x;

  for (int i = tid; i < 16 * 196; i += 256)
    xin[i / 196][i % 196] = x[(size_t)b * IMG_ + (size_t)(c0 + i / 196) * 196 + (i % 196)];
  if (tid < 144) wgt[tid / 9][tid % 9] = dww[(size_t)c0 * 9 + tid];
  __syncthreads();

  if (tid < 224) {
    const int cc = tid / 14;
    const int y0 = tid % 14;
    float w00 = wgt[cc][0], w01 = wgt[cc][1], w02 = wgt[cc][2];
    float w10 = wgt[cc][3], w11 = wgt[cc][4], w12 = wgt[cc][5];
    float w20 = wgt[cc][6], w21 = wgt[cc][7], w22 = wgt[cc][8];
    #pragma unroll
    for (int xx = 0; xx < 14; ++xx) {
      float acc = 0.f;
      #pragma unroll
      for (int ky = 0; ky < 3; ++ky) {
        int yy = y0 + ky - 1;
        bool yok = (yy >= 0) && (yy <= 13);
        #pragma unroll
        for (int kx = 0; kx < 3; ++kx) {
          int xs = xx + kx - 1;
          if (xs < 0 || xs > 13) continue;
          float wv = (ky == 0) ? (kx == 0 ? w00 : kx == 1 ? w01 : w02)
                   : (ky == 1) ? (kx == 0 ? w10 : kx == 1 ? w11 : w12)
                               : (kx == 0 ? w20 : kx == 1 ? w21 : w22);
          if (yok) acc += xin[cc][yy * 14 + xs] * wv;
        }
      }
      outT[y0 * 14 + xx][cc] = f2bf(acc);
    }
  }
  __syncthreads();
  for (int i = tid; i < 196 * 16; i += 256) {
    int pix = i >> 4, cc = i & 15;
    featT[(size_t)(b * 196 + pix) * DIM_ + (c0 + cc)] = outT[pix][cc];
  }
}

// ---------------------------------------------------------------------------
// Circular conv as per-channel MFMA GEMM over batch:
// Out_c[b][po] = sum_pin X2[b][pin] * T_c[po][pin],
// T_c[po][pin] = wsp[c][((yo-yi)%14)*14 + ((xo-xi)%14)].
// Block = 1 channel, 4 waves (each 32 batch rows), N=208 (13 frags), K=224.
// ---------------------------------------------------------------------------
__global__ __launch_bounds__(256) void k_circmm(
    const float* __restrict__ x, const float* __restrict__ wsp,
    unsigned short* __restrict__ feat2) {
  __shared__ __align__(16) unsigned short As[128 * 72];   // [b][72]
  __shared__ __align__(16) unsigned short Bs[208 * 72];   // [po][72]
  const int c = blockIdx.x;               // 0..383 filter idx
  const int tid = threadIdx.x;
  const int lane = tid & 63;
  const int wv = tid >> 6;
  const int fr = lane & 15, fg = lane >> 4;
  const float* xc = x + (size_t)(HALF_ + c) * 196;   // + b*IMG_
  const float* wspc = wsp + (size_t)c * 196;

  f32x4 acc[2][13];
  #pragma unroll
  for (int mi = 0; mi < 2; ++mi)
    #pragma unroll
    for (int ni = 0; ni < 13; ++ni) acc[mi][ni] = (f32x4)0.0f;

  for (int kt = 0; kt < 4; ++kt) {
    for (int i = tid; i < 2048; i += 256) {
      int b = i >> 4, jj = i & 15;
      int k = kt * 64 + jj * 4;
      ushort4 st = {0, 0, 0, 0};
      if (k < 196) {
        float4 v = *reinterpret_cast<const float4*>(xc + (size_t)b * IMG_ + k);
        st.x = f2bf(v.x); st.y = f2bf(v.y); st.z = f2bf(v.z); st.w = f2bf(v.w);
      }
      *reinterpret_cast<ushort4*>(&As[b * 72 + jj * 4]) = st;
    }
    for (int i = tid; i < 12544; i += 256) {
      int po = i >> 6, kl = i & 63;
      int pi = kt * 64 + kl;
      unsigned short w = 0;
      if (pi < 196) {
        int yo = po / 14, xo = po - yo * 14;
        int yi = pi / 14, xi = pi - yi * 14;
        int dy = yo - yi; dy += (dy >> 31) & 14;
        int dx = xo - xi; dx += (dx >> 31) & 14;
        w = f2bf(wspc[dy * 14 + dx]);
      }
      Bs[po * 72 + kl] = w;
    }
    __syncthreads();
    #pragma unroll
    for (int ks = 0; ks < 64; ks += 32) {
      bf16x8 a0 = *reinterpret_cast<const bf16x8*>(&As[(wv * 32 + fr) * 72 + ks + fg * 8]);
      bf16x8 a1 = *reinterpret_cast<const bf16x8*>(&As[(wv * 32 + 16 + fr) * 72 + ks + fg * 8]);
      #pragma unroll
      for (int ni = 0; ni < 13; ++ni) {
        bf16x8 bv = *reinterpret_cast<const bf16x8*>(&Bs[(ni * 16 + fr) * 72 + ks + fg * 8]);
        acc[0][ni] = __builtin_amdgcn_mfma_f32_16x16x32_bf16(a0, bv, acc[0][ni], 0, 0, 0);
        acc[1][ni] = __builtin_amdgcn_mfma_f32_16x16x32_bf16(a1, bv, acc[1][ni], 0, 0, 0);
      }
    }
    __syncthreads();
  }

  unsigned short* f2c = feat2 + (size_t)c * NPOS_;
  #pragma unroll
  for (int mi = 0; mi < 2; ++mi) {
    int b0 = wv * 32 + mi * 16 + fg * 4;
    #pragma unroll
    for (int ni = 0; ni < 13; ++ni) {
      int p = ni * 16 + fr;
      if (p < 196) {
        #pragma unroll
        for (int j = 0; j < 4; ++j)
          f2c[(size_t)(b0 + j) * 196 + p] = f2bf(acc[mi][ni][j]);
      }
    }
  }
}

// ---------------------------------------------------------------------------
// Transpose feat2[c][n] -> featT[n][384+c].  Tile 64c x 256n.
// ---------------------------------------------------------------------------
__global__ __launch_bounds__(256) void k_tr(
    const unsigned short* __restrict__ feat2, unsigned short* __restrict__ featT) {
  __shared__ __align__(16) unsigned short T2[64 * 264];
  const int n0 = blockIdx.x * 256;
  const int c0 = blockIdx.y * 64;
  const int tid = threadIdx.x;

  #pragma unroll
  for (int p = 0; p < 8; ++p) {
    int i = tid + p * 256;
    int c_l = i >> 5, nj = i & 31;
    uint4 v = *reinterpret_cast<const uint4*>(feat2 + (size_t)(c0 + c_l) * NPOS_ + n0 + nj * 8);
    *reinterpret_cast<uint4*>(&T2[c_l * 264 + nj * 8]) = v;
  }
  __syncthreads();
  #pragma unroll
  for (int p = 0; p < 8; ++p) {
    int i = tid + p * 256;
    int n_l = i >> 3, cj = i & 7;
    unsigned short vs[8];
    #pragma unroll
    for (int k = 0; k < 8; ++k) vs[k] = T2[(cj * 8 + k) * 264 + n_l];
    uint4 o;
    o.x = (unsigned int)vs[0] | ((unsigned int)vs[1] << 16);
    o.y = (unsigned int)vs[2] | ((unsigned int)vs[3] << 16);
    o.z = (unsigned int)vs[4] | ((unsigned int)vs[5] << 16);
    o.w = (unsigned int)vs[6] | ((unsigned int)vs[7] << 16);
    *reinterpret_cast<uint4*>(featT + (size_t)(n0 + n_l) * DIM_ + HALF_ + c0 + cj * 8) = o;
  }
}

// ---------------------------------------------------------------------------
// Proj GEMM (bf16 MFMA) + bias + fused BN partial stats (atomicAdd).
// global_load_lds width-16 staging (m97 structure).
// ---------------------------------------------------------------------------
__global__ __launch_bounds__(256) void k_gemm(
    const unsigned short* __restrict__ Wb, const unsigned short* __restrict__ featT,
    const float* __restrict__ bias, float* __restrict__ y, float* __restrict__ stats) {
  __shared__ __align__(16) unsigned short As[128 * 64];
  __shared__ __align__(16) unsigned short Bs[128 * 64];

  const int bx = blockIdx.x;          // n tile 0..195
  const int by = blockIdx.y;          // o tile 0..5
  const int tid = threadIdx.x;
  const int lane = tid & 63;
  const int wave = tid >> 6;
  const int wm = wave >> 1;
  const int wn = wave & 1;
  const int o_blk = by * 128;
  const int n_blk = bx * 128;

  f32x4 acc[4][4];
  #pragma unroll
  for (int i = 0; i < 4; ++i)
    #pragma unroll
    for (int j = 0; j < 4; ++j) acc[i][j] = (f32x4)0.0f;

  for (int kt = 0; kt < 768; kt += 64) {
    #pragma unroll
    for (int i = 0; i < 4; ++i) {
      int chunk = i * 256 + tid;
      int r = chunk >> 3;
      int cs = (chunk & 7) * 8;
      __builtin_amdgcn_global_load_lds(
          (gas_t)(Wb + (size_t)(o_blk + r) * 768 + kt + cs),
          (las_t)(&As[chunk * 8]), 16, 0, 0);
      __builtin_amdgcn_global_load_lds(
          (gas_t)(featT + (size_t)(n_blk + r) * 768 + kt + cs),
          (las_t)(&Bs[chunk * 8]), 16, 0, 0);
    }
    __syncthreads();
    #pragma unroll
    for (int ks = 0; ks < 64; ks += 32) {
      bf16x8 af[4], bfr[4];
      #pragma unroll
      for (int mi = 0; mi < 4; ++mi) {
        int row = wm * 64 + mi * 16 + (lane & 15);
        int col = ks + (lane >> 4) * 8;
        af[mi] = *reinterpret_cast<const bf16x8*>(&As[row * 64 + col]);
      }
      #pragma unroll
      for (int ni = 0; ni < 4; ++ni) {
        int row = wn * 64 + ni * 16 + (lane & 15);
        int col = ks + (lane >> 4) * 8;
        bfr[ni] = *reinterpret_cast<const bf16x8*>(&Bs[row * 64 + col]);
      }
      #pragma unroll
      for (int mi = 0; mi < 4; ++mi)
        #pragma unroll
        for (int ni = 0; ni < 4; ++ni)
          acc[mi][ni] = __builtin_amdgcn_mfma_f32_16x16x32_bf16(af[mi], bfr[ni], acc[mi][ni], 0, 0, 0);
    }
    __syncthreads();
  }

  const int col_l = lane & 15;
  #pragma unroll
  for (int mi = 0; mi < 4; ++mi) {
    const int o0 = o_blk + wm * 64 + mi * 16 + (lane >> 4) * 4;
    float bs[4], sv[4], s2v[4];
    #pragma unroll
    for (int j = 0; j < 4; ++j) { bs[j] = bias[o0 + j]; sv[j] = 0.f; s2v[j] = 0.f; }
    #pragma unroll
    for (int ni = 0; ni < 4; ++ni) {
      int n = n_blk + wn * 64 + ni * 16 + col_l;
      int b = n / 196;
      int hw = n % 196;
      size_t base = (size_t)b * IMG_ + (size_t)o0 * 196 + hw;
      #pragma unroll
      for (int j = 0; j < 4; ++j) {
        float v = acc[mi][ni][j] + bs[j];
        y[base + j * 196] = v;
        sv[j] += v; s2v[j] += v * v;
      }
    }
    #pragma unroll
    for (int j = 0; j < 4; ++j) {
      float a = sv[j], q = s2v[j];
      #pragma unroll
      for (int m = 1; m < 16; m <<= 1) { a += __shfl_xor(a, m); q += __shfl_xor(q, m); }
      if (col_l == 0) {
        atomicAdd(&stats[o0 + j], a);
        atomicAdd(&stats[DIM_ + o0 + j], q);
      }
    }
  }
}

// ---------------------------------------------------------------------------
// Normalize + affine from raw sums
// ---------------------------------------------------------------------------
__global__ void k_bnapply(float* __restrict__ y, const float* __restrict__ stats,
                          const float* __restrict__ gamma, const float* __restrict__ beta) {
  const size_t total4 = (size_t)B_ * DIM_ * HW_ / 4;
  const size_t stride = (size_t)gridDim.x * blockDim.x;
  for (size_t i4 = (size_t)blockIdx.x * blockDim.x + threadIdx.x; i4 < total4; i4 += stride) {
    float4 v = reinterpret_cast<float4*>(y)[i4];
    size_t flat = i4 * 4;
    int o = (int)((flat / 196) % DIM_);
    float mean = stats[o] * (1.f / (float)NPOS_);
    float var = stats[DIM_ + o] * (1.f / (float)NPOS_) - mean * mean;
    float g = gamma[o] * rsqrtf(var + 1e-5f);
    float be = beta[o] - mean * g;
    v.x = v.x * g + be; v.y = v.y * g + be; v.z = v.z * g + be; v.w = v.w * g + be;
    reinterpret_cast<float4*>(y)[i4] = v;
  }
}

extern "C" void kernel_launch(void* const* d_in, const int* in_sizes, int n_in,
                              void* d_out, int out_size, void* d_ws, size_t ws_size,
                              hipStream_t stream) {
  const float* x     = (const float*)d_in[0];
  const float* dww   = (const float*)d_in[1];
  const float* cw    = (const float*)d_in[2];
  const float* pw    = (const float*)d_in[3];
  const float* pb    = (const float*)d_in[4];
  const float* gamma = (const float*)d_in[5];
  const float* beta  = (const float*)d_in[6];
  float* out = (float*)d_out;

  char* wsb = (char*)d_ws;
  unsigned short* featT = (unsigned short*)wsb;                       // 38,535,168 B
  unsigned short* Wb    = (unsigned short*)(wsb + 38535168);          //  1,179,648 B
  float* wsp            = (float*)(wsb + 39714816);                   //    301,056 B
  unsigned short* feat2 = (unsigned short*)(wsb + 40015872);          // 19,267,584 B
  float* stats          = (float*)(wsb + 59283456);                   //      6,144 B

  k_zero<<<dim3(6), dim3(256), 0, stream>>>(stats);
  k_wspatial<<<dim3(HALF_), dim3(HW_), 0, stream>>>(cw, wsp);
  k_cvtW<<<dim3(576), dim3(256), 0, stream>>>(pw, Wb);
  k_dwconv<<<dim3(24, B_), dim3(256), 0, stream>>>(x, dww, featT);
  k_circmm<<<dim3(HALF_), dim3(256), 0, stream>>>(x, wsp, feat2);
  k_tr<<<dim3(98, 6), dim3(256), 0, stream>>>(feat2, featT);
  k_gemm<<<dim3(196, 6), dim3(256), 0, stream>>>(Wb, featT, pb, out, stats);
  k_bnapply<<<dim3(2048), dim3(256), 0, stream>>>(out, stats, gamma, beta);
}

// Round 5
// 378.971 us; speedup vs baseline: 1.0447x; 1.0447x over previous
//
#include <hip/hip_runtime.h>

typedef __attribute__((ext_vector_type(8))) __bf16 bf16x8;
typedef __attribute__((ext_vector_type(4))) float f32x4;

#define B_    128
#define DIM_  768
#define HALF_ 384
#define HW_   196
#define NPOS_ (B_*HW_)      /* 25088 */
#define IMG_  (DIM_*HW_)    /* 150528 */

typedef const __attribute__((address_space(1))) void* gas_t;
typedef __attribute__((address_space(3))) void* las_t;

__device__ __forceinline__ unsigned short f2bf(float f) {
  unsigned int u = __builtin_bit_cast(unsigned int, f);
  u = (u + 0x7FFFu + ((u >> 16) & 1u)) >> 16;
  return (unsigned short)u;
}

// ---------------------------------------------------------------------------
// Zero the BN stats accumulator (d_ws is poisoned 0xAA before every launch).
// ---------------------------------------------------------------------------
__global__ void k_zero(float* __restrict__ stats) {
  int i = blockIdx.x * 256 + threadIdx.x;
  if (i < 2 * DIM_) stats[i] = 0.f;
}

// ---------------------------------------------------------------------------
// w_spatial[c][y*14+x] from complex_weight (validated round 1)
// ---------------------------------------------------------------------------
__global__ void k_wspatial(const float* __restrict__ cw, float* __restrict__ wsp) {
  __shared__ float ct[14], st[14];
  const int c = blockIdx.x;
  const int tid = threadIdx.x;     // 0..195
  if (tid < 14) {
    float s, co;
    sincosf(0.44879895051282760549f * (float)tid, &s, &co);
    ct[tid] = co; st[tid] = s;
  }
  __syncthreads();
  const int y = tid / 14, xx = tid % 14;
  float acc = 0.f;
  for (int u = 0; u < 14; ++u) {
    #pragma unroll
    for (int v = 0; v < 8; ++v) {
      int idx = (u * y + v * xx) % 14;
      float wr = cw[(((size_t)c * 14 + u) * 8 + v) * 2 + 0];
      float wi = cw[(((size_t)c * 14 + u) * 8 + v) * 2 + 1];
      float fac = (v == 0 || v == 7) ? 1.f : 2.f;
      acc += fac * (wr * ct[idx] - wi * st[idx]);
    }
  }
  wsp[(size_t)c * 196 + tid] = acc * (1.f / 196.f);
}

// ---------------------------------------------------------------------------
// proj_weight fp32 -> bf16 [o][c]
// ---------------------------------------------------------------------------
__global__ void k_cvtW(const float* __restrict__ pw, unsigned short* __restrict__ Wb) {
  int i = blockIdx.x * 256 + threadIdx.x;
  float4 v = reinterpret_cast<const float4*>(pw)[i];
  unsigned int lo = (unsigned int)f2bf(v.x) | ((unsigned int)f2bf(v.y) << 16);
  unsigned int hi = (unsigned int)f2bf(v.z) | ((unsigned int)f2bf(v.w) << 16);
  reinterpret_cast<uint2*>(Wb)[i] = make_uint2(lo, hi);
}

// ---------------------------------------------------------------------------
// Depthwise 3x3 SAME (channels 0..383) -> featT[n][c] bf16
// ---------------------------------------------------------------------------
__global__ __launch_bounds__(256) void k_dwconv(
    const float* __restrict__ x, const float* __restrict__ dww,
    unsigned short* __restrict__ featT) {
  __shared__ __align__(16) float xin[16][196];
  __shared__ float wgt[16][9];
  __shared__ __align__(16) unsigned short outT[196][16];
  const int cgrp = blockIdx.x;
  const int b = blockIdx.y;
  const int c0 = cgrp * 16;
  const int tid = threadIdx.x;

  for (int i = tid; i < 16 * 196; i += 256)
    xin[i / 196][i % 196] = x[(size_t)b * IMG_ + (size_t)(c0 + i / 196) * 196 + (i % 196)];
  if (tid < 144) wgt[tid / 9][tid % 9] = dww[(size_t)c0 * 9 + tid];
  __syncthreads();

  if (tid < 224) {
    const int cc = tid / 14;
    const int y0 = tid % 14;
    float w00 = wgt[cc][0], w01 = wgt[cc][1], w02 = wgt[cc][2];
    float w10 = wgt[cc][3], w11 = wgt[cc][4], w12 = wgt[cc][5];
    float w20 = wgt[cc][6], w21 = wgt[cc][7], w22 = wgt[cc][8];
    #pragma unroll
    for (int xx = 0; xx < 14; ++xx) {
      float acc = 0.f;
      #pragma unroll
      for (int ky = 0; ky < 3; ++ky) {
        int yy = y0 + ky - 1;
        bool yok = (yy >= 0) && (yy <= 13);
        #pragma unroll
        for (int kx = 0; kx < 3; ++kx) {
          int xs = xx + kx - 1;
          if (xs < 0 || xs > 13) continue;
          float wv = (ky == 0) ? (kx == 0 ? w00 : kx == 1 ? w01 : w02)
                   : (ky == 1) ? (kx == 0 ? w10 : kx == 1 ? w11 : w12)
                               : (kx == 0 ? w20 : kx == 1 ? w21 : w22);
          if (yok) acc += xin[cc][yy * 14 + xs] * wv;
        }
      }
      outT[y0 * 14 + xx][cc] = f2bf(acc);
    }
  }
  __syncthreads();
  for (int i = tid; i < 196 * 16; i += 256) {
    int pix = i >> 4, cc = i & 15;
    featT[(size_t)(b * 196 + pix) * DIM_ + (c0 + cc)] = outT[pix][cc];
  }
}

// ---------------------------------------------------------------------------
// Circular conv as per-channel MFMA GEMM over batch (validated round 4).
// ---------------------------------------------------------------------------
__global__ __launch_bounds__(256) void k_circmm(
    const float* __restrict__ x, const float* __restrict__ wsp,
    unsigned short* __restrict__ feat2) {
  __shared__ __align__(16) unsigned short As[128 * 72];   // [b][72]
  __shared__ __align__(16) unsigned short Bs[208 * 72];   // [po][72]
  const int c = blockIdx.x;               // 0..383 filter idx
  const int tid = threadIdx.x;
  const int lane = tid & 63;
  const int wv = tid >> 6;
  const int fr = lane & 15, fg = lane >> 4;
  const float* xc = x + (size_t)(HALF_ + c) * 196;   // + b*IMG_
  const float* wspc = wsp + (size_t)c * 196;

  f32x4 acc[2][13];
  #pragma unroll
  for (int mi = 0; mi < 2; ++mi)
    #pragma unroll
    for (int ni = 0; ni < 13; ++ni) acc[mi][ni] = (f32x4)0.0f;

  for (int kt = 0; kt < 4; ++kt) {
    for (int i = tid; i < 2048; i += 256) {
      int b = i >> 4, jj = i & 15;
      int k = kt * 64 + jj * 4;
      ushort4 st = {0, 0, 0, 0};
      if (k < 196) {
        float4 v = *reinterpret_cast<const float4*>(xc + (size_t)b * IMG_ + k);
        st.x = f2bf(v.x); st.y = f2bf(v.y); st.z = f2bf(v.z); st.w = f2bf(v.w);
      }
      *reinterpret_cast<ushort4*>(&As[b * 72 + jj * 4]) = st;
    }
    for (int i = tid; i < 12544; i += 256) {
      int po = i >> 6, kl = i & 63;
      int pi = kt * 64 + kl;
      unsigned short w = 0;
      if (pi < 196) {
        int yo = po / 14, xo = po - yo * 14;
        int yi = pi / 14, xi = pi - yi * 14;
        int dy = yo - yi; dy += (dy >> 31) & 14;
        int dx = xo - xi; dx += (dx >> 31) & 14;
        w = f2bf(wspc[dy * 14 + dx]);
      }
      Bs[po * 72 + kl] = w;
    }
    __syncthreads();
    #pragma unroll
    for (int ks = 0; ks < 64; ks += 32) {
      bf16x8 a0 = *reinterpret_cast<const bf16x8*>(&As[(wv * 32 + fr) * 72 + ks + fg * 8]);
      bf16x8 a1 = *reinterpret_cast<const bf16x8*>(&As[(wv * 32 + 16 + fr) * 72 + ks + fg * 8]);
      #pragma unroll
      for (int ni = 0; ni < 13; ++ni) {
        bf16x8 bv = *reinterpret_cast<const bf16x8*>(&Bs[(ni * 16 + fr) * 72 + ks + fg * 8]);
        acc[0][ni] = __builtin_amdgcn_mfma_f32_16x16x32_bf16(a0, bv, acc[0][ni], 0, 0, 0);
        acc[1][ni] = __builtin_amdgcn_mfma_f32_16x16x32_bf16(a1, bv, acc[1][ni], 0, 0, 0);
      }
    }
    __syncthreads();
  }

  unsigned short* f2c = feat2 + (size_t)c * NPOS_;
  #pragma unroll
  for (int mi = 0; mi < 2; ++mi) {
    int b0 = wv * 32 + mi * 16 + fg * 4;
    #pragma unroll
    for (int ni = 0; ni < 13; ++ni) {
      int p = ni * 16 + fr;
      if (p < 196) {
        #pragma unroll
        for (int j = 0; j < 4; ++j)
          f2c[(size_t)(b0 + j) * 196 + p] = f2bf(acc[mi][ni][j]);
      }
    }
  }
}

// ---------------------------------------------------------------------------
// Transpose feat2[c][n] -> featT[n][384+c].  Tile 64c x 256n.
// ---------------------------------------------------------------------------
__global__ __launch_bounds__(256) void k_tr(
    const unsigned short* __restrict__ feat2, unsigned short* __restrict__ featT) {
  __shared__ __align__(16) unsigned short T2[64 * 264];
  const int n0 = blockIdx.x * 256;
  const int c0 = blockIdx.y * 64;
  const int tid = threadIdx.x;

  #pragma unroll
  for (int p = 0; p < 8; ++p) {
    int i = tid + p * 256;
    int c_l = i >> 5, nj = i & 31;
    uint4 v = *reinterpret_cast<const uint4*>(feat2 + (size_t)(c0 + c_l) * NPOS_ + n0 + nj * 8);
    *reinterpret_cast<uint4*>(&T2[c_l * 264 + nj * 8]) = v;
  }
  __syncthreads();
  #pragma unroll
  for (int p = 0; p < 8; ++p) {
    int i = tid + p * 256;
    int n_l = i >> 3, cj = i & 7;
    unsigned short vs[8];
    #pragma unroll
    for (int k = 0; k < 8; ++k) vs[k] = T2[(cj * 8 + k) * 264 + n_l];
    uint4 o;
    o.x = (unsigned int)vs[0] | ((unsigned int)vs[1] << 16);
    o.y = (unsigned int)vs[2] | ((unsigned int)vs[3] << 16);
    o.z = (unsigned int)vs[4] | ((unsigned int)vs[5] << 16);
    o.w = (unsigned int)vs[6] | ((unsigned int)vs[7] << 16);
    *reinterpret_cast<uint4*>(featT + (size_t)(n0 + n_l) * DIM_ + HALF_ + c0 + cj * 8) = o;
  }
}

// ---------------------------------------------------------------------------
// Proj GEMM (bf16 MFMA) + bias + fused BN partial stats.
// BK=32, double-buffered LDS (2x16KB), 2-phase schedule, XOR-swizzled tiles:
//   staging chunk (r,j) pulls global col-block (j^(r&3)); reader of col-slot
//   fg reads LDS slot fg^(row&3).  global_load_lds dest stays LINEAR (rule 21).
// ---------------------------------------------------------------------------
__global__ __launch_bounds__(256) void k_gemm(
    const unsigned short* __restrict__ Wb, const unsigned short* __restrict__ featT,
    const float* __restrict__ bias, float* __restrict__ y, float* __restrict__ stats) {
  __shared__ __align__(16) unsigned short As[2][4096];   // [buf][row*32 + slot*8 + e]
  __shared__ __align__(16) unsigned short Bs[2][4096];

  const int bx = blockIdx.x;          // n tile 0..195
  const int by = blockIdx.y;          // o tile 0..5
  const int tid = threadIdx.x;
  const int lane = tid & 63;
  const int wave = tid >> 6;
  const int wm = wave >> 1;
  const int wn = wave & 1;
  const int o_blk = by * 128;
  const int n_blk = bx * 128;
  const int fr = lane & 15, fg = lane >> 4;

  // staging constants: chunks tid and tid+256 (512 chunks of 16B per array)
  const int r0 = tid >> 2,         j0 = tid & 3;
  const int r1 = (tid + 256) >> 2, j1 = (tid + 256) & 3;
  const unsigned short* srcA0 = Wb    + (size_t)(o_blk + r0) * 768 + ((j0 ^ (r0 & 3)) << 3);
  const unsigned short* srcA1 = Wb    + (size_t)(o_blk + r1) * 768 + ((j1 ^ (r1 & 3)) << 3);
  const unsigned short* srcB0 = featT + (size_t)(n_blk + r0) * 768 + ((j0 ^ (r0 & 3)) << 3);
  const unsigned short* srcB1 = featT + (size_t)(n_blk + r1) * 768 + ((j1 ^ (r1 & 3)) << 3);
  const int ldsOff0 = tid << 3;            // chunk*8 elems
  const int ldsOff1 = (tid << 3) + 2048;

  // fragment read offsets (elements), swizzled
  int offA[4], offB[4];
  #pragma unroll
  for (int mi = 0; mi < 4; ++mi) {
    int row = wm * 64 + mi * 16 + fr;
    offA[mi] = (row << 5) + ((fg ^ (row & 3)) << 3);
  }
  #pragma unroll
  for (int ni = 0; ni < 4; ++ni) {
    int row = wn * 64 + ni * 16 + fr;
    offB[ni] = (row << 5) + ((fg ^ (row & 3)) << 3);
  }

  f32x4 acc[4][4];
  #pragma unroll
  for (int i = 0; i < 4; ++i)
    #pragma unroll
    for (int j = 0; j < 4; ++j) acc[i][j] = (f32x4)0.0f;

#define STAGE(buf, kt) do { \
    __builtin_amdgcn_global_load_lds((gas_t)(srcA0 + (kt)), (las_t)(&As[buf][ldsOff0]), 16, 0, 0); \
    __builtin_amdgcn_global_load_lds((gas_t)(srcB0 + (kt)), (las_t)(&Bs[buf][ldsOff0]), 16, 0, 0); \
    __builtin_amdgcn_global_load_lds((gas_t)(srcA1 + (kt)), (las_t)(&As[buf][ldsOff1]), 16, 0, 0); \
    __builtin_amdgcn_global_load_lds((gas_t)(srcB1 + (kt)), (las_t)(&Bs[buf][ldsOff1]), 16, 0, 0); \
  } while (0)

  STAGE(0, 0);
  asm volatile("s_waitcnt vmcnt(0)" ::: "memory");
  __syncthreads();

  int cur = 0;
  for (int t = 0; t < 24; ++t) {
    if (t < 23) STAGE(cur ^ 1, (t + 1) * 32);   // prefetch next K-tile
    bf16x8 af[4], bfv[4];
    #pragma unroll
    for (int mi = 0; mi < 4; ++mi)
      af[mi] = *reinterpret_cast<const bf16x8*>(&As[cur][offA[mi]]);
    #pragma unroll
    for (int ni = 0; ni < 4; ++ni)
      bfv[ni] = *reinterpret_cast<const bf16x8*>(&Bs[cur][offB[ni]]);
    #pragma unroll
    for (int mi = 0; mi < 4; ++mi)
      #pragma unroll
      for (int ni = 0; ni < 4; ++ni)
        acc[mi][ni] = __builtin_amdgcn_mfma_f32_16x16x32_bf16(af[mi], bfv[ni], acc[mi][ni], 0, 0, 0);
    asm volatile("s_waitcnt vmcnt(0)" ::: "memory");
    __syncthreads();
    cur ^= 1;
  }
#undef STAGE

  const int col_l = lane & 15;
  #pragma unroll
  for (int mi = 0; mi < 4; ++mi) {
    const int o0 = o_blk + wm * 64 + mi * 16 + (lane >> 4) * 4;
    float bs[4], sv[4], s2v[4];
    #pragma unroll
    for (int j = 0; j < 4; ++j) { bs[j] = bias[o0 + j]; sv[j] = 0.f; s2v[j] = 0.f; }
    #pragma unroll
    for (int ni = 0; ni < 4; ++ni) {
      int n = n_blk + wn * 64 + ni * 16 + col_l;
      int b = n / 196;
      int hw = n % 196;
      size_t base = (size_t)b * IMG_ + (size_t)o0 * 196 + hw;
      #pragma unroll
      for (int j = 0; j < 4; ++j) {
        float v = acc[mi][ni][j] + bs[j];
        y[base + j * 196] = v;
        sv[j] += v; s2v[j] += v * v;
      }
    }
    #pragma unroll
    for (int j = 0; j < 4; ++j) {
      float a = sv[j], q = s2v[j];
      #pragma unroll
      for (int m = 1; m < 16; m <<= 1) { a += __shfl_xor(a, m); q += __shfl_xor(q, m); }
      if (col_l == 0) {
        atomicAdd(&stats[o0 + j], a);
        atomicAdd(&stats[DIM_ + o0 + j], q);
      }
    }
  }
}

// ---------------------------------------------------------------------------
// Normalize + affine from raw sums
// ---------------------------------------------------------------------------
__global__ void k_bnapply(float* __restrict__ y, const float* __restrict__ stats,
                          const float* __restrict__ gamma, const float* __restrict__ beta) {
  const size_t total4 = (size_t)B_ * DIM_ * HW_ / 4;
  const size_t stride = (size_t)gridDim.x * blockDim.x;
  for (size_t i4 = (size_t)blockIdx.x * blockDim.x + threadIdx.x; i4 < total4; i4 += stride) {
    float4 v = reinterpret_cast<float4*>(y)[i4];
    size_t flat = i4 * 4;
    int o = (int)((flat / 196) % DIM_);
    float mean = stats[o] * (1.f / (float)NPOS_);
    float var = stats[DIM_ + o] * (1.f / (float)NPOS_) - mean * mean;
    float g = gamma[o] * rsqrtf(var + 1e-5f);
    float be = beta[o] - mean * g;
    v.x = v.x * g + be; v.y = v.y * g + be; v.z = v.z * g + be; v.w = v.w * g + be;
    reinterpret_cast<float4*>(y)[i4] = v;
  }
}

extern "C" void kernel_launch(void* const* d_in, const int* in_sizes, int n_in,
                              void* d_out, int out_size, void* d_ws, size_t ws_size,
                              hipStream_t stream) {
  const float* x     = (const float*)d_in[0];
  const float* dww   = (const float*)d_in[1];
  const float* cw    = (const float*)d_in[2];
  const float* pw    = (const float*)d_in[3];
  const float* pb    = (const float*)d_in[4];
  const float* gamma = (const float*)d_in[5];
  const float* beta  = (const float*)d_in[6];
  float* out = (float*)d_out;

  char* wsb = (char*)d_ws;
  unsigned short* featT = (unsigned short*)wsb;                       // 38,535,168 B
  unsigned short* Wb    = (unsigned short*)(wsb + 38535168);          //  1,179,648 B
  float* wsp            = (float*)(wsb + 39714816);                   //    301,056 B
  unsigned short* feat2 = (unsigned short*)(wsb + 40015872);          // 19,267,584 B
  float* stats          = (float*)(wsb + 59283456);                   //      6,144 B

  k_zero<<<dim3(6), dim3(256), 0, stream>>>(stats);
  k_wspatial<<<dim3(HALF_), dim3(HW_), 0, stream>>>(cw, wsp);
  k_cvtW<<<dim3(576), dim3(256), 0, stream>>>(pw, Wb);
  k_dwconv<<<dim3(24, B_), dim3(256), 0, stream>>>(x, dww, featT);
  k_circmm<<<dim3(HALF_), dim3(256), 0, stream>>>(x, wsp, feat2);
  k_tr<<<dim3(98, 6), dim3(256), 0, stream>>>(feat2, featT);
  k_gemm<<<dim3(196, 6), dim3(256), 0, stream>>>(Wb, featT, pb, out, stats);
  k_bnapply<<<dim3(2048), dim3(256), 0, stream>>>(out, stats, gamma, beta);
}